// Round 9
// baseline (689.141 us; speedup 1.0000x reference)
//
#include <hip/hip_runtime.h>

#define LN_EPS 1e-5f
#define LOG2E 1.44269504f
#define NHALF_LOG2E (-0.72134752f)
#define NBLK 1024
#define SPIN_GUARD (1 << 20)

#if __has_builtin(__builtin_amdgcn_exp2f)
#define EXP2F(x) __builtin_amdgcn_exp2f(x)
#else
#define EXP2F(x) __expf((x) * 0.69314718f)
#endif

typedef float v2f __attribute__((ext_vector_type(2)));

__device__ __forceinline__ float silu_f(float v) {
    return v * __builtin_amdgcn_rcpf(1.f + EXP2F(-v * LOG2E));
}

// ---------------------------------------------------------------------------
// Zero the barrier counters (ws is re-poisoned 0xAA before every launch).
// 6 barriers x 576 ints (32 line-padded sub-counters + flag at [512]).
// ---------------------------------------------------------------------------
__global__ __launch_bounds__(576)
void init_ctr(int* __restrict__ ctr)
{
    ctr[blockIdx.x * 576 + threadIdx.x] = 0;
}

// ---------------------------------------------------------------------------
// Device-scope grid barrier. All NBLK blocks are co-resident by capacity
// (4 blocks/CU x 256 CU; LDS 36.9 KB/block, VGPR capped by launch_bounds).
// Arrive: per-thread threadfence (drains own stores to device visibility),
// block sync, tid0 adds to 1 of 32 line-padded sub-counters.
// Block 0's tid0 aggregates (32 independent relaxed loads/poll) and releases
// a single flag; others acquire-spin on the flag. Bounded spins: a failure
// produces a wrong answer, never a hang.
// ---------------------------------------------------------------------------
__device__ __forceinline__ void grid_barrier(int* base, int bx, int tid)
{
    __threadfence();
    __syncthreads();
    if (tid == 0) {
        atomicAdd(&base[(bx & 31) << 4], 1);
        if (bx == 0) {
            int guard = 0;
            for (;;) {
                int tot = 0;
#pragma unroll
                for (int j = 0; j < 32; ++j)
                    tot += __hip_atomic_load(&base[j << 4], __ATOMIC_RELAXED,
                                             __HIP_MEMORY_SCOPE_AGENT);
                if (tot >= NBLK || ++guard > SPIN_GUARD) break;
            }
            __threadfence();
            __hip_atomic_store(&base[512], 1, __ATOMIC_RELEASE,
                               __HIP_MEMORY_SCOPE_AGENT);
        } else {
            int guard = 0;
            while (__hip_atomic_load(&base[512], __ATOMIC_ACQUIRE,
                                     __HIP_MEMORY_SCOPE_AGENT) == 0) {
                if (++guard > SPIN_GUARD) break;
                __builtin_amdgcn_s_sleep(2);
            }
        }
    }
    __syncthreads();
}

union SharedU {
    struct { float2 A[2][16][96]; float W[2][16][96]; } p0;  // wav0: 36864 B
    struct { float2 A[2][4][32];  float W[2][4][32];  } p1;  // wav1/2: 3072 B
    struct { float r1[2], r2[2], cr[5][2]; } red;            // ln/cls
};

// ---------------------------------------------------------------------------
// Wavelet stage. Wave owns NO consecutive o's, i in [si*RANGE,(si+1)*RANGE).
// Lane = (p=lane&15 -> batches 2p,2p+1 ; g=lane>>4 -> i-subgroup).
// prep {inv,-t*inv,w} into per-wave LDS once; x slice loaded once into regs;
// o-loop rolled (store-per-o keeps VGPR low, body I-cache-friendly).
// part layout [si][b][o].
// ---------------------------------------------------------------------------
template<int KIN, int S, int NO>
__device__ __forceinline__ void wav_stage(int bx, int wave, int lane,
    const float* __restrict__ xT, const float* __restrict__ w,
    const float* __restrict__ t, const float* __restrict__ s,
    float* __restrict__ part, float2* prepA, float* prepW)
{
    constexpr int RANGE = KIN / S;
    constexpr int STEPS = RANGE / 4;
    constexpr int OGRP = 512 / (2 * NO);   // o-groups; OGRP*S == NBLK
    const int og = bx % OGRP;
    const int si = bx / OGRP;
    const int obase = (og * 2 + wave) * NO;
    const int ibase = si * RANGE;
    float2* pA = prepA + wave * (NO * RANGE);
    float*  pW = prepW + wave * (NO * RANGE);

#pragma unroll
    for (int e = lane; e < NO * RANGE; e += 64) {
        int ol = e / RANGE, il = e - ol * RANGE;
        size_t gi = (size_t)(obase + ol) * KIN + ibase + il;
        float wv = w[gi], tv = t[gi], sv = s[gi];
        float sig = __builtin_amdgcn_rcpf(1.f + EXP2F(-sv * LOG2E));
        float inv = __builtin_amdgcn_rcpf(fmaf(9.99f, sig, 0.01000001f));
        pA[ol * RANGE + il] = make_float2(inv, -tv * inv);
        pW[ol * RANGE + il] = wv;
    }
    __syncthreads();

    const int p = lane & 15, g = lane >> 4;
    const v2f* __restrict__ xp = (const v2f*)xT + (size_t)(ibase + g) * 16 + p;
    v2f xr[STEPS];
#pragma unroll
    for (int st = 0; st < STEPS; ++st) xr[st] = xp[(size_t)st * 64];

    for (int ol = 0; ol < NO; ++ol) {
        v2f acc = {0.f, 0.f};
#pragma unroll
        for (int st = 0; st < STEPS; ++st) {
            float2 pr = pA[ol * RANGE + st * 4 + g];
            float  wj = pW[ol * RANGE + st * 4 + g];
            v2f u  = __builtin_elementwise_fma(xr[st], (v2f){pr.x, pr.x},
                                               (v2f){pr.y, pr.y});
            v2f q  = u * u;
            v2f ev = {EXP2F(q.x * NHALF_LOG2E), EXP2F(q.y * NHALF_LOG2E)};
            v2f pw = __builtin_elementwise_fma((v2f){-wj, -wj}, q,
                                               (v2f){wj, wj});   // w*(1-q)
            acc = __builtin_elementwise_fma(pw, ev, acc);
        }
        float a0 = acc.x, a1 = acc.y;
        a0 += __shfl_down(a0, 32); a0 += __shfl_down(a0, 16);
        a1 += __shfl_down(a1, 32); a1 += __shfl_down(a1, 16);
        if (lane < 16) {
            float* bp = part + (size_t)si * 16384 + obase + ol;
            bp[(2 * p) * 512]     = a0;
            bp[(2 * p + 1) * 512] = a1;
        }
    }
}

// ---------------------------------------------------------------------------
// Sum S slices of part[si][b][o] (float4, coalesced) + silu + LN(512).
// One block per batch row b (128 threads x 4 o). Writes hT[o][b].
// ---------------------------------------------------------------------------
template<int S>
__device__ __forceinline__ void ln_stage(int b, int tid,
    const float* __restrict__ part, const float* __restrict__ g,
    const float* __restrict__ bias, float* __restrict__ hT,
    float* r1, float* r2)
{
    const int o0 = tid * 4;
    float v0 = 0.f, v1 = 0.f, v2 = 0.f, v3 = 0.f;
#pragma unroll
    for (int si = 0; si < S; ++si) {
        float4 pv = *(const float4*)(part + (size_t)si * 16384 + b * 512 + o0);
        v0 += pv.x; v1 += pv.y; v2 += pv.z; v3 += pv.w;
    }
    float a0 = silu_f(v0), a1 = silu_f(v1), a2 = silu_f(v2), a3 = silu_f(v3);
    float s1 = a0 + a1 + a2 + a3;
    float s2 = a0*a0 + a1*a1 + a2*a2 + a3*a3;
#pragma unroll
    for (int off = 32; off; off >>= 1) {
        s1 += __shfl_down(s1, off);
        s2 += __shfl_down(s2, off);
    }
    const int lane = tid & 63, wid = tid >> 6;
    if (lane == 0) { r1[wid] = s1; r2[wid] = s2; }
    __syncthreads();
    float t1 = r1[0] + r1[1], t2 = r2[0] + r2[1];
    float m   = t1 * (1.f / 512.f);
    float var = t2 * (1.f / 512.f) - m * m;
    float r   = __builtin_amdgcn_rsqf(var + LN_EPS);
    hT[(o0 + 0) * 32 + b] = (a0 - m) * r * g[o0 + 0] + bias[o0 + 0];
    hT[(o0 + 1) * 32 + b] = (a1 - m) * r * g[o0 + 1] + bias[o0 + 1];
    hT[(o0 + 2) * 32 + b] = (a2 - m) * r * g[o0 + 2] + bias[o0 + 2];
    hT[(o0 + 3) * 32 + b] = (a3 - m) * r * g[o0 + 3] + bias[o0 + 3];
}

// ---------------------------------------------------------------------------
// Final: sum + silu + LN + classifier (out[b][c] = hln . cw[c] + cb[c]).
// ---------------------------------------------------------------------------
template<int S>
__device__ __forceinline__ void cls_stage(int b, int tid,
    const float* __restrict__ part, const float* __restrict__ g,
    const float* __restrict__ bias, const float* __restrict__ cw,
    const float* __restrict__ cb, float* __restrict__ out,
    float* r1, float* r2, float* cr)
{
    const int o0 = tid * 4;
    float v0 = 0.f, v1 = 0.f, v2 = 0.f, v3 = 0.f;
#pragma unroll
    for (int si = 0; si < S; ++si) {
        float4 pv = *(const float4*)(part + (size_t)si * 16384 + b * 512 + o0);
        v0 += pv.x; v1 += pv.y; v2 += pv.z; v3 += pv.w;
    }
    float a0 = silu_f(v0), a1 = silu_f(v1), a2 = silu_f(v2), a3 = silu_f(v3);
    float s1 = a0 + a1 + a2 + a3;
    float s2 = a0*a0 + a1*a1 + a2*a2 + a3*a3;
#pragma unroll
    for (int off = 32; off; off >>= 1) {
        s1 += __shfl_down(s1, off);
        s2 += __shfl_down(s2, off);
    }
    const int lane = tid & 63, wid = tid >> 6;
    if (lane == 0) { r1[wid] = s1; r2[wid] = s2; }
    __syncthreads();
    float t1 = r1[0] + r1[1], t2 = r2[0] + r2[1];
    float m   = t1 * (1.f / 512.f);
    float var = t2 * (1.f / 512.f) - m * m;
    float r   = __builtin_amdgcn_rsqf(var + LN_EPS);
    float h0 = (a0 - m) * r * g[o0 + 0] + bias[o0 + 0];
    float h1 = (a1 - m) * r * g[o0 + 1] + bias[o0 + 1];
    float h2 = (a2 - m) * r * g[o0 + 2] + bias[o0 + 2];
    float h3 = (a3 - m) * r * g[o0 + 3] + bias[o0 + 3];
#pragma unroll
    for (int c = 0; c < 5; ++c) {
        const float* cwr = cw + c * 512 + o0;
        float pv = h0 * cwr[0] + h1 * cwr[1] + h2 * cwr[2] + h3 * cwr[3];
#pragma unroll
        for (int off = 32; off; off >>= 1) pv += __shfl_down(pv, off);
        if (lane == 0) cr[c * 2 + wid] = pv;
    }
    __syncthreads();
    if (tid < 5) out[b * 5 + tid] = cr[tid * 2] + cr[tid * 2 + 1] + cb[tid];
}

// ---------------------------------------------------------------------------
// One persistent kernel: transpose | wav0 | ln0 | wav1 | ln1 | wav2 | ln+cls
// separated by 6 device-scope grid barriers. Grid 1024x128 is co-resident:
// LDS 36.9 KB -> 4 blocks/CU x 256 CU = 1024; launch_bounds caps VGPR at 128.
// ---------------------------------------------------------------------------
__global__ __launch_bounds__(128, 4)
void fused(const float* __restrict__ x,
           const float* __restrict__ w0, const float* __restrict__ t0,
           const float* __restrict__ s0, const float* __restrict__ g0,
           const float* __restrict__ b0,
           const float* __restrict__ w1, const float* __restrict__ t1,
           const float* __restrict__ s1, const float* __restrict__ g1,
           const float* __restrict__ b1,
           const float* __restrict__ w2, const float* __restrict__ t2,
           const float* __restrict__ s2, const float* __restrict__ g2,
           const float* __restrict__ b2,
           const float* __restrict__ cw, const float* __restrict__ cb,
           float* __restrict__ out,
           float* __restrict__ xT, float* __restrict__ pA,
           float* __restrict__ pB, float* __restrict__ pC,
           float* __restrict__ hT, float* __restrict__ h2T,
           int* __restrict__ ctr)
{
    __shared__ SharedU sh;
    const int bx   = blockIdx.x;
    const int tid  = threadIdx.x;
    const int wave = tid >> 6, lane = tid & 63;

    // S0: transpose x (32 x 6144) -> xT (6144 x 32)
    {
        int idx = bx * 128 + tid;
        xT[idx] = x[(idx & 31) * 6144 + (idx >> 5)];
        int idx2 = idx + 131072;
        if (idx2 < 196608) xT[idx2] = x[(idx2 & 31) * 6144 + (idx2 >> 5)];
    }
    grid_barrier(ctr + 0 * 576, bx, tid);

    // S1: wav layer 0 (NO=16, S=64, RANGE=96)
    wav_stage<6144, 64, 16>(bx, wave, lane, xT, w0, t0, s0, pA,
                            &sh.p0.A[0][0][0], &sh.p0.W[0][0][0]);
    grid_barrier(ctr + 1 * 576, bx, tid);

    if (bx < 32) ln_stage<64>(bx, tid, pA, g0, b0, hT, sh.red.r1, sh.red.r2);
    grid_barrier(ctr + 2 * 576, bx, tid);

    // S3: wav layer 1 (NO=4, S=16, RANGE=32)
    wav_stage<512, 16, 4>(bx, wave, lane, hT, w1, t1, s1, pB,
                          &sh.p1.A[0][0][0], &sh.p1.W[0][0][0]);
    grid_barrier(ctr + 3 * 576, bx, tid);

    if (bx < 32) ln_stage<16>(bx, tid, pB, g1, b1, h2T, sh.red.r1, sh.red.r2);
    grid_barrier(ctr + 4 * 576, bx, tid);

    // S5: wav layer 2
    wav_stage<512, 16, 4>(bx, wave, lane, h2T, w2, t2, s2, pC,
                          &sh.p1.A[0][0][0], &sh.p1.W[0][0][0]);
    grid_barrier(ctr + 5 * 576, bx, tid);

    if (bx < 32) cls_stage<16>(bx, tid, pC, g2, b2, cw, cb, out,
                               sh.red.r1, sh.red.r2, &sh.red.cr[0][0]);
}

extern "C" void kernel_launch(void* const* d_in, const int* in_sizes, int n_in,
                              void* d_out, int out_size, void* d_ws, size_t ws_size,
                              hipStream_t stream)
{
    const float* x  = (const float*)d_in[0];
    const float* w0 = (const float*)d_in[1];
    const float* t0 = (const float*)d_in[2];
    const float* s0 = (const float*)d_in[3];
    const float* g0 = (const float*)d_in[4];
    const float* b0 = (const float*)d_in[5];
    const float* w1 = (const float*)d_in[6];
    const float* t1 = (const float*)d_in[7];
    const float* s1 = (const float*)d_in[8];
    const float* g1 = (const float*)d_in[9];
    const float* b1 = (const float*)d_in[10];
    const float* w2 = (const float*)d_in[11];
    const float* t2 = (const float*)d_in[12];
    const float* s2 = (const float*)d_in[13];
    const float* g2 = (const float*)d_in[14];
    const float* b2 = (const float*)d_in[15];
    const float* cw = (const float*)d_in[16];
    const float* cb = (const float*)d_in[17];
    float* out = (float*)d_out;

    // ws layout: ctr (6*576 ints, pad to 4096) | floats: xT 196608 |
    // pA 64*16384 | pB 16*16384 | pC 16*16384 | hT 16384 | h2T 16384
    int*   ctr = (int*)d_ws;
    float* xT  = (float*)d_ws + 4096;
    float* pA  = xT + 196608;
    float* pB  = pA + 64 * 16384;
    float* pC  = pB + 16 * 16384;
    float* hT  = pC + 16 * 16384;
    float* h2T = hT + 16384;

    init_ctr<<<6, 576, 0, stream>>>(ctr);
    fused<<<NBLK, 128, 0, stream>>>(x, w0, t0, s0, g0, b0,
                                    w1, t1, s1, g1, b1,
                                    w2, t2, s2, g2, b2,
                                    cw, cb, out,
                                    xT, pA, pB, pC, hT, h2T, ctr);
}